// Round 1
// baseline (6381.229 us; speedup 1.0000x reference)
//
#include <hip/hip_runtime.h>
#include <math.h>

// ---------------------------------------------------------------------------
// DyRes/CondConv AlexNet forward, fp32 end-to-end.
// Strategy: every conv is a single implicit-im2col GEMM with the expert mix
// folded into the K dimension (A = experts concat along K, B-tile loader
// applies r[b,e] scale + gather). FC layers are plain GEMMs on [feat, batch]
// layout activations.
// ---------------------------------------------------------------------------

__global__ __launch_bounds__(64)
void stats_kernel(const float* __restrict__ act, float* __restrict__ s,
                  int Bsz, int C, int HW, int cbhw, int use_std)
{
    int idx = blockIdx.x;           // b*C + c
    int b = idx / C, c = idx - b * C;
    size_t base = cbhw ? ((size_t)c * Bsz + b) : ((size_t)b * C + c);
    const float* p = act + base * HW;
    int lane = threadIdx.x;
    float sum = 0.f, sq = 0.f;
    for (int i = lane; i < HW; i += 64) { float v = p[i]; sum += v; sq += v * v; }
#pragma unroll
    for (int off = 32; off > 0; off >>= 1) {
        sum += __shfl_down(sum, off);
        sq  += __shfl_down(sq, off);
    }
    if (lane == 0) {
        float inv = 1.f / (float)HW;
        float mean = sum * inv;
        float var = sq * inv - mean * mean;
        float outv = mean;
        if (use_std) outv += sqrtf(fmaxf(var, 0.f));
        s[idx] = outv;
    }
}

// r[b,e] = softmax_e / sigmoid of (s[b,:] @ rw.T + rb), E = 3
__global__ __launch_bounds__(64)
void routing_kernel(const float* __restrict__ s, const float* __restrict__ rw,
                    const float* __restrict__ rb, float* __restrict__ r,
                    int C, int softmax_mode)
{
    int b = blockIdx.x;
    int lane = threadIdx.x;
    float d0 = 0.f, d1 = 0.f, d2 = 0.f;
    for (int c = lane; c < C; c += 64) {
        float sv = s[b * C + c];
        d0 += sv * rw[c];
        d1 += sv * rw[C + c];
        d2 += sv * rw[2 * C + c];
    }
#pragma unroll
    for (int off = 32; off > 0; off >>= 1) {
        d0 += __shfl_down(d0, off);
        d1 += __shfl_down(d1, off);
        d2 += __shfl_down(d2, off);
    }
    if (lane == 0) {
        d0 += rb[0]; d1 += rb[1]; d2 += rb[2];
        if (softmax_mode) {
            float mx = fmaxf(d0, fmaxf(d1, d2));
            float e0 = expf(d0 - mx), e1 = expf(d1 - mx), e2 = expf(d2 - mx);
            float inv = 1.f / (e0 + e1 + e2);
            r[b * 3 + 0] = e0 * inv;
            r[b * 3 + 1] = e1 * inv;
            r[b * 3 + 2] = e2 * inv;
        } else {
            r[b * 3 + 0] = 1.f / (1.f + expf(-d0));
            r[b * 3 + 1] = 1.f / (1.f + expf(-d1));
            r[b * 3 + 2] = 1.f / (1.f + expf(-d2));
        }
    }
}

// ---------------------------------------------------------------------------
// Tiled GEMM: C[M,N] = op(A)[M,Ktot] * op(B)[Ktot,N]   (64x64 tile, 4x4/thread)
// BMODE: 0 = plain B[k*N+n]
//        1 = implicit im2col from act [Ci,Bsz,H,W], scaled by r[b,e]
//        2 = implicit im2col from act [Bsz,Ci,H,W] (layer-1 input), r-scaled
// AEXPERT: A[m,kk] = dw[(e*M+m)*Kper + k]  (experts concat along K)
// ---------------------------------------------------------------------------
template<int BMODE, int AEXPERT, int BIAS, int RELU, int TROUT>
__global__ __launch_bounds__(256)
void gemm_kernel(const float* __restrict__ A, const float* __restrict__ Bm,
                 const float* __restrict__ rptr, const float* __restrict__ bias,
                 float* __restrict__ Cout,
                 int M, int N, int Ktot, int Kper,
                 int Ci, int Bsz, int H, int W, int lgS, int lgOW, int stride)
{
    __shared__ float As[16 * 68];   // [k][m], stride 68 (pad: kills 16-way store conflict, keeps 16B align)
    __shared__ float Bs[16 * 64];   // [k][n]
    const int tid = threadIdx.x;
    const int bx = blockIdx.x, by = blockIdx.y;
    const int tx = tid & 15, ty = tid >> 4;
    const int tk = tid & 15, tm0 = tid >> 4;
    const int tn = tid & 63, tkb = tid >> 6;
    const int n0 = bx << 6;
    const int ngB = n0 + tn;
    float acc[4][4] = {{0.f}};

    // n-side conv indices are k-independent: hoist out of the K loop
    int bB = 0, ohB = 0, owB = 0;
    float rB0 = 0.f, rB1 = 0.f, rB2 = 0.f;
    if (BMODE != 0) {
        bB = ngB >> lgS;
        int sidx = ngB & ((1 << lgS) - 1);
        ohB = sidx >> lgOW;
        owB = sidx & ((1 << lgOW) - 1);
        rB0 = rptr[bB * 3 + 0];
        rB1 = rptr[bB * 3 + 1];
        rB2 = rptr[bB * 3 + 2];
    }

    for (int k0 = 0; k0 < Ktot; k0 += 16) {
        // ---- stage A tile ----
        {
            int kk = k0 + tk;
            int e = 0, kq = kk;
            if (AEXPERT) {
                e = (kk >= Kper) ? ((kk >= 2 * Kper) ? 2 : 1) : 0;
                kq = kk - e * Kper;
            }
#pragma unroll
            for (int i = 0; i < 4; ++i) {
                int m = tm0 + i * 16;
                int mg = (by << 6) + m;
                float v = 0.f;
                if (kk < Ktot && mg < M) {
                    if (AEXPERT) v = A[((size_t)(e * M + mg)) * Kper + kq];
                    else         v = A[(size_t)mg * Ktot + kk];
                }
                As[tk * 68 + m] = v;
            }
        }
        // ---- stage B tile ----
#pragma unroll
        for (int j = 0; j < 4; ++j) {
            int kloc = (tkb << 2) + j;
            int kk = k0 + kloc;
            float v = 0.f;
            if (kk < Ktot) {
                if (BMODE == 0) {
                    v = Bm[(size_t)kk * N + ngB];
                } else {
                    int e = (kk >= Kper) ? ((kk >= 2 * Kper) ? 2 : 1) : 0;
                    int kq = kk - e * Kper;
                    int ci = kq / 9;                 // const-div -> magic mul
                    int rrem = kq - ci * 9;
                    int kh = rrem / 3;
                    int kw = rrem - kh * 3;
                    int ih = ohB * stride - 1 + kh;
                    int iw = owB * stride - 1 + kw;
                    if ((unsigned)ih < (unsigned)H && (unsigned)iw < (unsigned)W) {
                        size_t aidx;
                        if (BMODE == 2) aidx = (((size_t)bB * Ci + ci) * H + ih) * W + iw;
                        else            aidx = (((size_t)ci * Bsz + bB) * H + ih) * W + iw;
                        float rs = (e == 0) ? rB0 : ((e == 1) ? rB1 : rB2);
                        v = Bm[aidx] * rs;
                    }
                }
            }
            Bs[kloc * 64 + tn] = v;
        }
        __syncthreads();
        // ---- compute ----
#pragma unroll
        for (int k = 0; k < 16; ++k) {
            float4 av = *(const float4*)(&As[k * 68 + (ty << 2)]);
            float4 bv = *(const float4*)(&Bs[(k << 6) + (tx << 2)]);
            float a4[4] = {av.x, av.y, av.z, av.w};
            float b4[4] = {bv.x, bv.y, bv.z, bv.w};
#pragma unroll
            for (int i = 0; i < 4; ++i)
#pragma unroll
                for (int j = 0; j < 4; ++j)
                    acc[i][j] = fmaf(a4[i], b4[j], acc[i][j]);
        }
        __syncthreads();
    }

    // ---- epilogue ----
#pragma unroll
    for (int i = 0; i < 4; ++i) {
        int mg = (by << 6) + (ty << 2) + i;
        if (mg >= M) continue;
        float bv = BIAS ? bias[mg] : 0.f;
#pragma unroll
        for (int j = 0; j < 4; ++j) {
            int ng = n0 + (tx << 2) + j;
            if (ng >= N) continue;
            float v = acc[i][j] + bv;
            if (RELU) v = fmaxf(v, 0.f);
            if (TROUT) Cout[(size_t)ng * M + mg] = v;   // out[b*M + m]
            else       Cout[(size_t)mg * N + ng] = v;   // [feat, batch*spatial]
        }
    }
}

// 2x2/2 maxpool on [CB, H, W] -> [CB, H/2, W/2]
__global__ __launch_bounds__(256)
void pool_kernel(const float* __restrict__ in, float* __restrict__ out,
                 int CB, int H, int W)
{
    int OH = H >> 1, OW = W >> 1;
    int total = CB * OH * OW;
    int i = blockIdx.x * 256 + threadIdx.x;
    if (i >= total) return;
    int ow = i % OW;
    int t = i / OW;
    int oh = t % OH;
    int cb = t / OH;
    const float* p = in + ((size_t)cb * H + (oh << 1)) * W + (ow << 1);
    out[i] = fmaxf(fmaxf(p[0], p[1]), fmaxf(p[W], p[W + 1]));
}

// conv5 out [256,512,4,4] --pool2x2--> flatten to hT [1024, 512] (feature-major)
__global__ __launch_bounds__(256)
void pool_flatten_kernel(const float* __restrict__ in, float* __restrict__ out)
{
    int i = blockIdx.x * 256 + threadIdx.x;     // over 256*512*4
    if (i >= 256 * 512 * 4) return;
    int b = i & 511;
    int t = i >> 9;
    int s = t & 3;          // oh*2+ow of pooled 2x2
    int c = t >> 2;
    int oh = s >> 1, ow = s & 1;
    const float* p = in + (((size_t)c * 512 + b) * 4 + (oh << 1)) * 4 + (ow << 1);
    float v = fmaxf(fmaxf(p[0], p[1]), fmaxf(p[4], p[5]));
    out[(size_t)(c * 4 + s) * 512 + b] = v;
}

extern "C" void kernel_launch(void* const* d_in, const int* in_sizes, int n_in,
                              void* d_out, int out_size, void* d_ws, size_t ws_size,
                              hipStream_t stream)
{
    const float* x    = (const float*)d_in[0];
    const float* dw1  = (const float*)d_in[1];
    const float* rw1  = (const float*)d_in[2];
    const float* rb1  = (const float*)d_in[3];
    const float* dw2  = (const float*)d_in[4];
    const float* rw2  = (const float*)d_in[5];
    const float* rb2  = (const float*)d_in[6];
    const float* dw3  = (const float*)d_in[7];
    const float* rw3  = (const float*)d_in[8];
    const float* rb3  = (const float*)d_in[9];
    const float* cw4  = (const float*)d_in[10];
    const float* cr4w = (const float*)d_in[11];
    const float* cr4b = (const float*)d_in[12];
    const float* cw5  = (const float*)d_in[13];
    const float* cr5w = (const float*)d_in[14];
    const float* cr5b = (const float*)d_in[15];
    const float* fw1  = (const float*)d_in[16];
    const float* fb1  = (const float*)d_in[17];
    const float* fw2  = (const float*)d_in[18];
    const float* fb2  = (const float*)d_in[19];
    const float* fw3  = (const float*)d_in[20];
    const float* fb3  = (const float*)d_in[21];
    float* out = (float*)d_out;

    // workspace layout (floats); total ~14.9M floats = ~60 MB
    float* ws    = (float*)d_ws;
    float* r1    = ws;
    float* r2    = r1 + 1536;
    float* r3    = r2 + 1536;
    float* r4    = r3 + 1536;
    float* r5    = r4 + 1536;
    float* sdesc = ws + 8192;               // 512*384 max
    float* slabA = sdesc + 196608;          // 8,388,608 floats (c1/c2/c3/c5/f2)
    float* slabB = slabA + 8388608;         // 2,097,152 floats (c4/f1)
    float* a1    = slabB + 2097152;         // 2,097,152 (pooled1; later f2 input reuse)
    float* a2    = a1 + 2097152;            // 1,572,864 (pooled2)
    float* hT    = a2 + 1572864;            // 524,288

    const int B = 512;

    // ---- Layer 1: DyRes conv 3->64, stride 2, pad 1 -> c1 [64, 512*16*16] ----
    stats_kernel<<<B * 3, 64, 0, stream>>>(x, sdesc, B, 3, 1024, 0, 1);
    routing_kernel<<<B, 64, 0, stream>>>(sdesc, rw1, rb1, r1, 3, 1);
    gemm_kernel<2, 1, 0, 1, 0><<<dim3(131072 / 64, 1), 256, 0, stream>>>(
        dw1, x, r1, nullptr, slabA, 64, 131072, 81, 27, 3, B, 32, 32, 8, 4, 2);
    pool_kernel<<<(64 * 512 * 64) / 256, 256, 0, stream>>>(slabA, a1, 64 * 512, 16, 16);

    // ---- Layer 2: DyRes conv 64->192 -> c2 [192, 512*8*8] ----
    stats_kernel<<<B * 64, 64, 0, stream>>>(a1, sdesc, B, 64, 64, 1, 1);
    routing_kernel<<<B, 64, 0, stream>>>(sdesc, rw2, rb2, r2, 64, 1);
    gemm_kernel<1, 1, 0, 1, 0><<<dim3(32768 / 64, 3), 256, 0, stream>>>(
        dw2, a1, r2, nullptr, slabA, 192, 32768, 1728, 576, 64, B, 8, 8, 6, 3, 1);
    pool_kernel<<<(192 * 512 * 16) / 256, 256, 0, stream>>>(slabA, a2, 192 * 512, 8, 8);

    // ---- Layer 3: DyRes conv 192->384 -> c3 [384, 512*4*4] ----
    stats_kernel<<<B * 192, 64, 0, stream>>>(a2, sdesc, B, 192, 16, 1, 1);
    routing_kernel<<<B, 64, 0, stream>>>(sdesc, rw3, rb3, r3, 192, 1);
    gemm_kernel<1, 1, 0, 1, 0><<<dim3(8192 / 64, 6), 256, 0, stream>>>(
        dw3, a2, r3, nullptr, slabA, 384, 8192, 5184, 1728, 192, B, 4, 4, 4, 2, 1);

    // ---- Layer 4: CondConv 384->256 -> c4 [256, 8192] (reads slabA, writes slabB) ----
    stats_kernel<<<B * 384, 64, 0, stream>>>(slabA, sdesc, B, 384, 16, 1, 0);
    routing_kernel<<<B, 64, 0, stream>>>(sdesc, cr4w, cr4b, r4, 384, 0);
    gemm_kernel<1, 1, 0, 1, 0><<<dim3(8192 / 64, 4), 256, 0, stream>>>(
        cw4, slabA, r4, nullptr, slabB, 256, 8192, 10368, 3456, 384, B, 4, 4, 4, 2, 1);

    // ---- Layer 5: CondConv 256->256 -> c5 [256, 8192] (reads slabB, writes slabA) ----
    stats_kernel<<<B * 256, 64, 0, stream>>>(slabB, sdesc, B, 256, 16, 1, 0);
    routing_kernel<<<B, 64, 0, stream>>>(sdesc, cr5w, cr5b, r5, 256, 0);
    gemm_kernel<1, 1, 0, 1, 0><<<dim3(8192 / 64, 4), 256, 0, stream>>>(
        cw5, slabB, r5, nullptr, slabA, 256, 8192, 6912, 2304, 256, B, 4, 4, 4, 2, 1);

    // ---- pool + flatten -> hT [1024, 512] ----
    pool_flatten_kernel<<<(256 * 512 * 4) / 256, 256, 0, stream>>>(slabA, hT);

    // ---- FC1: 1024 -> 4096, relu -> slabB [4096, 512] ----
    gemm_kernel<0, 0, 1, 1, 0><<<dim3(8, 64), 256, 0, stream>>>(
        fw1, hT, nullptr, fb1, slabB, 4096, 512, 1024, 0, 0, 0, 0, 0, 0, 0, 0);
    // ---- FC2: 4096 -> 4096, relu -> a1 [4096, 512] ----
    gemm_kernel<0, 0, 1, 1, 0><<<dim3(8, 64), 256, 0, stream>>>(
        fw2, slabB, nullptr, fb2, a1, 4096, 512, 4096, 0, 0, 0, 0, 0, 0, 0, 0);
    // ---- FC3: 4096 -> 100, transposed store into d_out [512, 100] ----
    gemm_kernel<0, 0, 1, 0, 1><<<dim3(8, 2), 256, 0, stream>>>(
        fw3, a1, nullptr, fb3, out, 100, 512, 4096, 0, 0, 0, 0, 0, 0, 0, 0);
}